// Round 3
// baseline (506.676 us; speedup 1.0000x reference)
//
#include <hip/hip_runtime.h>
#include <hip/hip_bf16.h>

#define N_NODES 50000
#define M_PAD   50048          // 391 * 128
#define N_EDGES 800000
#define NEG_SLOPE 0.2f

#define SCAN_BLK 512
#define SCAN_NB ((N_NODES + SCAN_BLK - 1) / SCAN_BLK)   // 98

typedef __attribute__((ext_vector_type(8))) short bf16x8;
typedef __attribute__((ext_vector_type(4))) float f32x4;

__device__ __forceinline__ unsigned short f2bf(float f) {
    unsigned u = __float_as_uint(f);
    u += 0x7FFFu + ((u >> 16) & 1u);          // RNE
    return (unsigned short)(u >> 16);
}
__device__ __forceinline__ float bf2f(unsigned short h) {
    return __uint_as_float(((unsigned)h) << 16);
}

// async global->LDS, 16B per lane; LDS dest = wave-uniform base + lane*16
__device__ __forceinline__ void gload_lds16(const void* g, void* l) {
    __builtin_amdgcn_global_load_lds(
        (const __attribute__((address_space(1))) unsigned int*)g,
        (__attribute__((address_space(3))) unsigned int*)l,
        16, 0, 0);
}

// ---------------- CSR build ----------------

__global__ __launch_bounds__(256) void k_hist(const int* __restrict__ dst, int* __restrict__ deg) {
    int i = blockIdx.x * 256 + threadIdx.x;
    if (i < N_EDGES) atomicAdd(&deg[dst[i]], 1);
}

__global__ __launch_bounds__(SCAN_BLK) void k_scan1(const int* __restrict__ deg,
                                                    int* __restrict__ rowoff,
                                                    int* __restrict__ bsum) {
    __shared__ int s[SCAN_BLK];
    int i = blockIdx.x * SCAN_BLK + threadIdx.x;
    int v = (i < N_NODES) ? deg[i] : 0;
    s[threadIdx.x] = v;
    __syncthreads();
    for (int off = 1; off < SCAN_BLK; off <<= 1) {
        int t = (threadIdx.x >= off) ? s[threadIdx.x - off] : 0;
        __syncthreads();
        s[threadIdx.x] += t;
        __syncthreads();
    }
    if (i < N_NODES) rowoff[i] = s[threadIdx.x];
    if (threadIdx.x == SCAN_BLK - 1) bsum[blockIdx.x] = s[SCAN_BLK - 1];
}

__global__ __launch_bounds__(128) void k_scan2(int* __restrict__ bsum) {
    __shared__ int s[128];
    int t = threadIdx.x;
    int v = (t < SCAN_NB) ? bsum[t] : 0;
    s[t] = v;
    __syncthreads();
    for (int off = 1; off < 128; off <<= 1) {
        int x = (t >= off) ? s[t - off] : 0;
        __syncthreads();
        s[t] += x;
        __syncthreads();
    }
    if (t < SCAN_NB) bsum[t] = s[t] - v;  // exclusive
}

__global__ __launch_bounds__(SCAN_BLK) void k_scan3(const int* __restrict__ deg,
                                                    int* __restrict__ rowoff,
                                                    int* __restrict__ wp,
                                                    const int* __restrict__ bsum) {
    int i = blockIdx.x * SCAN_BLK + threadIdx.x;
    if (i < N_NODES) {
        int excl = rowoff[i] - deg[i] + bsum[blockIdx.x];
        rowoff[i] = excl;
        wp[i] = excl;
    }
    if (i == 0) rowoff[N_NODES] = N_EDGES;
}

__global__ __launch_bounds__(256) void k_scatter(const int* __restrict__ src, const int* __restrict__ dst,
                                                 int* __restrict__ wp, int* __restrict__ csr_src) {
    int i = blockIdx.x * 256 + threadIdx.x;
    if (i < N_EDGES) {
        int p = atomicAdd(&wp[dst[i]], 1);
        csr_src[p] = src[i];
    }
}

// ---------------- x -> bf16 (padded rows zeroed) ----------------

__global__ __launch_bounds__(256) void k_xcast(const float* __restrict__ x, unsigned short* __restrict__ xb) {
    size_t i = (size_t)(blockIdx.x * 256 + threadIdx.x) * 8;
    if (i >= (size_t)M_PAD * 256) return;
    float4 a = make_float4(0.f, 0.f, 0.f, 0.f), b = a;
    if (i < (size_t)N_NODES * 256) {
        a = *(const float4*)(x + i);
        b = *(const float4*)(x + i + 4);
    }
    ushort4 h0, h1;
    h0.x = f2bf(a.x); h0.y = f2bf(a.y); h0.z = f2bf(a.z); h0.w = f2bf(a.w);
    h1.x = f2bf(b.x); h1.y = f2bf(b.y); h1.z = f2bf(b.z); h1.w = f2bf(b.w);
    *(ushort4*)(xb + i) = h0;
    *(ushort4*)(xb + i + 4) = h1;
}

// ---------------- weight transpose + bf16: in[K][Nn] f32 -> out[n][K] bf16 ----------------

__global__ __launch_bounds__(256) void k_trans(const float* __restrict__ in, unsigned short* __restrict__ out,
                                               int K, int Nn) {
    __shared__ unsigned short tile[32][33];
    int tx = threadIdx.x & 31, ty = threadIdx.x >> 5;  // 32 x 8
    int n0 = blockIdx.x * 32, k0 = blockIdx.y * 32;
    #pragma unroll
    for (int r = 0; r < 4; ++r) {
        int k = k0 + ty + r * 8;
        tile[ty + r * 8][tx] = f2bf(in[(size_t)k * Nn + n0 + tx]);
    }
    __syncthreads();
    #pragma unroll
    for (int r = 0; r < 4; ++r) {
        int n = ty + r * 8;
        out[(size_t)(n0 + n) * K + k0 + tx] = tile[tx][n];
    }
}

// ---------------- GEMM1 (MFMA bf16, async staging): feat1b = xb @ W1T^T ----------------
// A: xb [M_PAD][256] bf16. B: W1T [256 n][256 k] bf16. Unpadded LDS (global_load_lds layout).

__global__ __launch_bounds__(256) void k_gemm1(const unsigned short* __restrict__ xb,
                                               const unsigned short* __restrict__ BT,
                                               unsigned short* __restrict__ Cb) {
    __shared__ unsigned short As[128 * 32];
    __shared__ unsigned short Bs[128 * 32];
    const int t = threadIdx.x;
    const int bm0 = blockIdx.x * 128;
    const int bn0 = blockIdx.y * 128;
    const int wave = t >> 6, lane = t & 63;
    const int wm = (wave & 1) * 64, wn = (wave >> 1) * 64;
    const int lm = lane & 15, quad = lane >> 4;
    const int lrow = lane >> 2;          // 0..15
    const int lchk = (lane & 3) * 8;     // short offset

    f32x4 acc[4][4];
    #pragma unroll
    for (int i = 0; i < 4; ++i)
        #pragma unroll
        for (int j = 0; j < 4; ++j)
            #pragma unroll
            for (int r = 0; r < 4; ++r) acc[i][j][r] = 0.f;

    for (int k0 = 0; k0 < 256; k0 += 32) {
        #pragma unroll
        for (int i = 0; i < 2; ++i) {
            int r0 = wave * 32 + i * 16;
            gload_lds16(xb + (size_t)(bm0 + r0 + lrow) * 256 + k0 + lchk, &As[r0 * 32]);
            gload_lds16(BT + (size_t)(bn0 + r0 + lrow) * 256 + k0 + lchk, &Bs[r0 * 32]);
        }
        __syncthreads();
        bf16x8 af[4], bfr[4];
        #pragma unroll
        for (int i = 0; i < 4; ++i)
            af[i] = *(const bf16x8*)(&As[(wm + i * 16 + lm) * 32 + quad * 8]);
        #pragma unroll
        for (int i = 0; i < 4; ++i)
            bfr[i] = *(const bf16x8*)(&Bs[(wn + i * 16 + lm) * 32 + quad * 8]);
        #pragma unroll
        for (int mi = 0; mi < 4; ++mi)
            #pragma unroll
            for (int ni = 0; ni < 4; ++ni)
                acc[mi][ni] = __builtin_amdgcn_mfma_f32_16x16x32_bf16(af[mi], bfr[ni], acc[mi][ni], 0, 0, 0);
        __syncthreads();
    }
    #pragma unroll
    for (int mi = 0; mi < 4; ++mi) {
        #pragma unroll
        for (int ni = 0; ni < 4; ++ni) {
            int col = bn0 + wn + ni * 16 + lm;
            #pragma unroll
            for (int r = 0; r < 4; ++r) {
                int row = bm0 + wm + mi * 16 + quad * 4 + r;
                if (row < N_NODES)
                    Cb[(size_t)row * 256 + col] = f2bf(acc[mi][ni][r]);
            }
        }
    }
}

// ---------------- GEMM2 (MFMA bf16, async staging): [feat2b|res2] = y_b @ W2T^T ----------------

__global__ __launch_bounds__(256) void k_gemm2(const unsigned short* __restrict__ Ab,
                                               const unsigned short* __restrict__ BT,  // [64][256]
                                               unsigned short* __restrict__ feat2b, float* __restrict__ res2) {
    __shared__ unsigned short As[128 * 32];
    __shared__ unsigned short Bs[64 * 32];
    const int t = threadIdx.x;
    const int bm0 = blockIdx.x * 128;
    const int wave = t >> 6, lane = t & 63;
    const int wm = (wave & 1) * 64, wn = (wave >> 1) * 32;
    const int lm = lane & 15, quad = lane >> 4;
    const int lrow = lane >> 2;
    const int lchk = (lane & 3) * 8;

    f32x4 acc[4][2];
    #pragma unroll
    for (int i = 0; i < 4; ++i)
        #pragma unroll
        for (int j = 0; j < 2; ++j)
            #pragma unroll
            for (int r = 0; r < 4; ++r) acc[i][j][r] = 0.f;

    for (int k0 = 0; k0 < 256; k0 += 32) {
        #pragma unroll
        for (int i = 0; i < 2; ++i) {
            int r0 = wave * 32 + i * 16;
            gload_lds16(Ab + (size_t)(bm0 + r0 + lrow) * 256 + k0 + lchk, &As[r0 * 32]);
        }
        {
            int r0 = wave * 16;
            gload_lds16(BT + (size_t)(r0 + lrow) * 256 + k0 + lchk, &Bs[r0 * 32]);
        }
        __syncthreads();
        bf16x8 af[4], bfr[2];
        #pragma unroll
        for (int i = 0; i < 4; ++i)
            af[i] = *(const bf16x8*)(&As[(wm + i * 16 + lm) * 32 + quad * 8]);
        #pragma unroll
        for (int i = 0; i < 2; ++i)
            bfr[i] = *(const bf16x8*)(&Bs[(wn + i * 16 + lm) * 32 + quad * 8]);
        #pragma unroll
        for (int mi = 0; mi < 4; ++mi)
            #pragma unroll
            for (int ni = 0; ni < 2; ++ni)
                acc[mi][ni] = __builtin_amdgcn_mfma_f32_16x16x32_bf16(af[mi], bfr[ni], acc[mi][ni], 0, 0, 0);
        __syncthreads();
    }
    #pragma unroll
    for (int mi = 0; mi < 2 * 2; ++mi) {
        #pragma unroll
        for (int ni = 0; ni < 2; ++ni) {
            int col = wn + ni * 16 + lm;  // 0..63
            #pragma unroll
            for (int r = 0; r < 4; ++r) {
                int row = bm0 + wm + mi * 16 + quad * 4 + r;
                if (row < N_NODES) {
                    float val = acc[mi][ni][r];
                    if (col < 32) feat2b[(size_t)row * 32 + col] = f2bf(val);
                    else          res2[(size_t)row * 32 + col - 32] = val;
                }
            }
        }
    }
}

// ---------------- el1/er1 ----------------

__global__ __launch_bounds__(256) void k_elr1(const unsigned short* __restrict__ feat1b,
                                              const float* __restrict__ al1, const float* __restrict__ ar1,
                                              float* __restrict__ el1, float* __restrict__ er1) {
    int n = (blockIdx.x * 256 + threadIdx.x) >> 6;
    int lane = threadIdx.x & 63;
    if (n >= N_NODES) return;
    int c0 = lane * 4;
    ushort4 hv = *(const ushort4*)(feat1b + (size_t)n * 256 + c0);
    float4 a = *(const float4*)(al1 + c0);
    float4 r = *(const float4*)(ar1 + c0);
    float fx = bf2f(hv.x), fy = bf2f(hv.y), fz = bf2f(hv.z), fw = bf2f(hv.w);
    float pel = fx * a.x + fy * a.y + fz * a.z + fw * a.w;
    float per = fx * r.x + fy * r.y + fz * r.z + fw * r.w;
    #pragma unroll
    for (int off = 4; off >= 1; off >>= 1) {
        pel += __shfl_down(pel, off, 64);
        per += __shfl_down(per, off, 64);
    }
    if ((lane & 7) == 0) {
        el1[n * 8 + (lane >> 3)] = pel;
        er1[n * 8 + (lane >> 3)] = per;
    }
}

// ---------------- edge weights L1: alpha1[h][j] normalized, bf16 ----------------
// wave per dst node; lane: h = lane&7, ec = lane>>3 (8 edges/iter)

__global__ __launch_bounds__(256) void k_edgew1(const float* __restrict__ el1, const float* __restrict__ er1,
                                                const int* __restrict__ rowoff, const int* __restrict__ csr_src,
                                                unsigned short* __restrict__ alpha1) {
    int v = blockIdx.x * 4 + (threadIdx.x >> 6);
    int lane = threadIdx.x & 63;
    if (v >= N_NODES) return;
    int h = lane & 7, ec = lane >> 3;
    float er = er1[v * 8 + h];
    int s = rowoff[v], e = rowoff[v + 1];
    float wsum = 0.f;
    for (int j0 = s; j0 < e; j0 += 8) {
        int j = j0 + ec;
        float w = 0.f;
        if (j < e) {
            int u = csr_src[j];
            float t = el1[u * 8 + h] + er;
            t = t > 0.f ? t : NEG_SLOPE * t;
            w = __expf(t);
        }
        wsum += w;
    }
    #pragma unroll
    for (int m = 8; m <= 32; m <<= 1) wsum += __shfl_xor(wsum, m, 64);
    float inv = 1.f / wsum;
    for (int j0 = s; j0 < e; j0 += 8) {
        int j = j0 + ec;
        if (j < e) {
            int u = csr_src[j];
            float t = el1[u * 8 + h] + er;
            t = t > 0.f ? t : NEG_SLOPE * t;
            alpha1[(size_t)h * N_EDGES + j] = f2bf(__expf(t) * inv);
        }
    }
}

// ---------------- L1 aggregation, XCD-sliced: slice = one head = 32 cols ----------------
// blockIdx.x % 8 -> slice (XCD round-robin); per-XCD feat footprint = 3.2 MB (L2-resident)

__global__ __launch_bounds__(256) void k_agg1s(const unsigned short* __restrict__ feat1b,
                                               const unsigned short* __restrict__ alpha1,
                                               const float* __restrict__ x, const float* __restrict__ b1,
                                               const int* __restrict__ rowoff, const int* __restrict__ csr_src,
                                               unsigned short* __restrict__ y_b) {
    int slice = blockIdx.x & 7;
    int grp = blockIdx.x >> 3;
    int wave = threadIdx.x >> 6, lane = threadIdx.x & 63;
    int sub = lane >> 5, c = lane & 31;
    int v = grp * 8 + wave * 2 + sub;
    int col = slice * 32 + c;
    const unsigned short* ap = alpha1 + (size_t)slice * N_EDGES;
    float acc = 0.f;
    int s = rowoff[v], e = rowoff[v + 1];
    int j = s;
    for (; j + 1 < e; j += 2) {
        int u0 = csr_src[j], u1 = csr_src[j + 1];
        float a0 = bf2f(ap[j]), a1 = bf2f(ap[j + 1]);
        float f0 = bf2f(feat1b[(size_t)u0 * 256 + col]);
        float f1 = bf2f(feat1b[(size_t)u1 * 256 + col]);
        acc += a0 * f0 + a1 * f1;
    }
    if (j < e) {
        int u = csr_src[j];
        acc += bf2f(ap[j]) * bf2f(feat1b[(size_t)u * 256 + col]);
    }
    float r = x[(size_t)v * 256 + col];
    float o = fmaxf(acc + r + b1[col], 0.f);
    y_b[(size_t)v * 256 + col] = f2bf(o);
}

// ---------------- el2/er2 from bf16 feat2 ----------------

__global__ __launch_bounds__(256) void k_elr2(const unsigned short* __restrict__ feat2b,
                                              const float* __restrict__ al2, const float* __restrict__ ar2,
                                              float* __restrict__ el2, float* __restrict__ er2) {
    int n = blockIdx.x * 256 + threadIdx.x;
    if (n >= N_NODES) return;
    float el = 0.f, er = 0.f;
    #pragma unroll
    for (int q = 0; q < 8; ++q) {
        ushort4 hv = *(const ushort4*)(feat2b + (size_t)n * 32 + q * 4);
        float4 a = ((const float4*)al2)[q];
        float4 r = ((const float4*)ar2)[q];
        el += bf2f(hv.x) * a.x + bf2f(hv.y) * a.y + bf2f(hv.z) * a.z + bf2f(hv.w) * a.w;
        er += bf2f(hv.x) * r.x + bf2f(hv.y) * r.y + bf2f(hv.z) * r.z + bf2f(hv.w) * r.w;
    }
    el2[n] = el;
    er2[n] = er;
}

// ---------------- edge weights L2: alpha2[j], bf16 (1 head) ----------------

__global__ __launch_bounds__(256) void k_edgew2(const float* __restrict__ el2, const float* __restrict__ er2,
                                                const int* __restrict__ rowoff, const int* __restrict__ csr_src,
                                                unsigned short* __restrict__ alpha2) {
    int v = blockIdx.x * 4 + (threadIdx.x >> 6);
    int lane = threadIdx.x & 63;
    if (v >= N_NODES) return;
    float er = er2[v];
    int s = rowoff[v], e = rowoff[v + 1];
    float wsum = 0.f;
    for (int j0 = s; j0 < e; j0 += 64) {
        int j = j0 + lane;
        float w = 0.f;
        if (j < e) {
            float t = el2[csr_src[j]] + er;
            t = t > 0.f ? t : NEG_SLOPE * t;
            w = __expf(t);
        }
        wsum += w;
    }
    #pragma unroll
    for (int m = 1; m <= 32; m <<= 1) wsum += __shfl_xor(wsum, m, 64);
    float inv = 1.f / wsum;
    for (int j0 = s; j0 < e; j0 += 64) {
        int j = j0 + lane;
        if (j < e) {
            float t = el2[csr_src[j]] + er;
            t = t > 0.f ? t : NEG_SLOPE * t;
            alpha2[j] = f2bf(__expf(t) * inv);
        }
    }
}

// ---------------- L2 aggregation: 32 lanes per dst node ----------------

__global__ __launch_bounds__(256) void k_agg2(const unsigned short* __restrict__ feat2b,
                                              const unsigned short* __restrict__ alpha2,
                                              const float* __restrict__ res2, const float* __restrict__ b2,
                                              const int* __restrict__ rowoff, const int* __restrict__ csr_src,
                                              float* __restrict__ out) {
    int g = blockIdx.x * 256 + threadIdx.x;
    int v = g >> 5;
    int c = g & 31;
    if (v >= N_NODES) return;
    float acc = 0.f;
    int s = rowoff[v], e = rowoff[v + 1];
    int j = s;
    for (; j + 1 < e; j += 2) {
        int u0 = csr_src[j], u1 = csr_src[j + 1];
        float a0 = bf2f(alpha2[j]), a1 = bf2f(alpha2[j + 1]);
        acc += a0 * bf2f(feat2b[(size_t)u0 * 32 + c]) + a1 * bf2f(feat2b[(size_t)u1 * 32 + c]);
    }
    if (j < e)
        acc += bf2f(alpha2[j]) * bf2f(feat2b[(size_t)csr_src[j] * 32 + c]);
    out[(size_t)v * 32 + c] = acc + res2[(size_t)v * 32 + c] + b2[c];
}

// ---------------- launch ----------------

extern "C" void kernel_launch(void* const* d_in, const int* in_sizes, int n_in,
                              void* d_out, int out_size, void* d_ws, size_t ws_size,
                              hipStream_t stream) {
    const float* x     = (const float*)d_in[0];
    const int*   src   = (const int*)d_in[1];
    const int*   dst   = (const int*)d_in[2];
    const float* W1    = (const float*)d_in[3];
    const float* al1   = (const float*)d_in[4];
    const float* ar1   = (const float*)d_in[5];
    const float* b1    = (const float*)d_in[6];
    const float* W2    = (const float*)d_in[7];
    const float* al2   = (const float*)d_in[8];
    const float* ar2   = (const float*)d_in[9];
    const float* resW2 = (const float*)d_in[10];
    const float* b2    = (const float*)d_in[11];
    float* out = (float*)d_out;

    char* ws = (char*)d_ws;
    size_t off = 0;
    auto alloc = [&](size_t bytes) {
        void* p = ws + off;
        off += (bytes + 255) & ~(size_t)255;
        return p;
    };
    unsigned short* xb     = (unsigned short*)alloc((size_t)M_PAD * 256 * 2);
    unsigned short* feat1b = (unsigned short*)alloc((size_t)N_NODES * 256 * 2);
    unsigned short* y_b    = (unsigned short*)alloc((size_t)M_PAD * 256 * 2);
    unsigned short* W1T    = (unsigned short*)alloc((size_t)256 * 256 * 2);
    unsigned short* W2T    = (unsigned short*)alloc((size_t)64 * 256 * 2);
    unsigned short* alpha1 = (unsigned short*)alloc((size_t)8 * N_EDGES * 2);
    unsigned short* alpha2 = (unsigned short*)alloc((size_t)N_EDGES * 2);
    unsigned short* feat2b = (unsigned short*)alloc((size_t)N_NODES * 32 * 2);
    float* res2   = (float*)alloc((size_t)N_NODES * 32 * 4);
    float* el1    = (float*)alloc((size_t)N_NODES * 8 * 4);
    float* er1    = (float*)alloc((size_t)N_NODES * 8 * 4);
    float* el2    = (float*)alloc((size_t)N_NODES * 4);
    float* er2    = (float*)alloc((size_t)N_NODES * 4);
    int*   deg    = (int*)alloc((size_t)N_NODES * 4);
    int*   rowoff = (int*)alloc((size_t)(N_NODES + 1) * 4);
    int*   wp     = (int*)alloc((size_t)N_NODES * 4);
    int*   bsum   = (int*)alloc((size_t)SCAN_NB * 4);
    int*   csr    = (int*)alloc((size_t)N_EDGES * 4);
    (void)ws_size;

    // CSR build (rebuilt every call)
    hipMemsetAsync(deg, 0, (size_t)N_NODES * 4, stream);
    k_hist<<<(N_EDGES + 255) / 256, 256, 0, stream>>>(dst, deg);
    k_scan1<<<SCAN_NB, SCAN_BLK, 0, stream>>>(deg, rowoff, bsum);
    k_scan2<<<1, 128, 0, stream>>>(bsum);
    k_scan3<<<SCAN_NB, SCAN_BLK, 0, stream>>>(deg, rowoff, wp, bsum);
    k_scatter<<<(N_EDGES + 255) / 256, 256, 0, stream>>>(src, dst, wp, csr);

    // casts / transposes
    k_xcast<<<(M_PAD * 256 / 8 + 255) / 256, 256, 0, stream>>>(x, xb);
    k_trans<<<dim3(8, 8), 256, 0, stream>>>(W1, W1T, 256, 256);
    k_trans<<<dim3(1, 8), 256, 0, stream>>>(W2, W2T, 256, 32);
    k_trans<<<dim3(1, 8), 256, 0, stream>>>(resW2, W2T + 32 * 256, 256, 32);

    // Layer 1
    k_gemm1<<<dim3(M_PAD / 128, 2), 256, 0, stream>>>(xb, W1T, feat1b);
    k_elr1<<<(N_NODES * 64) / 256, 256, 0, stream>>>(feat1b, al1, ar1, el1, er1);
    k_edgew1<<<(N_NODES + 3) / 4, 256, 0, stream>>>(el1, er1, rowoff, csr, alpha1);
    k_agg1s<<<(N_NODES / 8) * 8, 256, 0, stream>>>(feat1b, alpha1, x, b1, rowoff, csr, y_b);

    // Layer 2
    k_gemm2<<<M_PAD / 128, 256, 0, stream>>>(y_b, W2T, feat2b, res2);
    k_elr2<<<(N_NODES + 255) / 256, 256, 0, stream>>>(feat2b, al2, ar2, el2, er2);
    k_edgew2<<<(N_NODES + 3) / 4, 256, 0, stream>>>(el2, er2, rowoff, csr, alpha2);
    k_agg2<<<(N_NODES * 32) / 256, 256, 0, stream>>>(feat2b, alpha2, res2, b2, rowoff, csr, out);
}

// Round 4
// 481.878 us; speedup vs baseline: 1.0515x; 1.0515x over previous
//
#include <hip/hip_runtime.h>
#include <hip/hip_bf16.h>

#define N_NODES 50000
#define M_PAD   50048          // 391 * 128
#define N_EDGES 800000
#define NEG_SLOPE 0.2f

typedef __attribute__((ext_vector_type(8))) short bf16x8;
typedef __attribute__((ext_vector_type(4))) float f32x4;

__device__ __forceinline__ unsigned short f2bf(float f) {
    unsigned u = __float_as_uint(f);
    u += 0x7FFFu + ((u >> 16) & 1u);          // RNE
    return (unsigned short)(u >> 16);
}
__device__ __forceinline__ float bf2f(unsigned short h) {
    return __uint_as_float(((unsigned)h) << 16);
}

// async global->LDS, 16B per lane; LDS dest = wave-uniform base + lane*16
__device__ __forceinline__ void gload_lds16(const void* g, void* l) {
    __builtin_amdgcn_global_load_lds(
        (const __attribute__((address_space(1))) unsigned int*)g,
        (__attribute__((address_space(3))) unsigned int*)l,
        16, 0, 0);
}

// ---------------- CSR build ----------------

__global__ __launch_bounds__(256) void k_hist(const int* __restrict__ dst, int* __restrict__ deg) {
    int i = blockIdx.x * 256 + threadIdx.x;
    if (i < N_EDGES) atomicAdd(&deg[dst[i]], 1);
}

// single-block scan: 1024 threads, each owns 49 contiguous elements
__global__ __launch_bounds__(1024) void k_scan(const int* __restrict__ deg,
                                               int* __restrict__ rowoff,
                                               int* __restrict__ wp) {
    __shared__ int s[1024];
    int t = threadIdx.x;
    int base = t * 49;
    int sum = 0;
    for (int i = 0; i < 49; ++i) {
        int idx = base + i;
        if (idx < N_NODES) sum += deg[idx];
    }
    s[t] = sum;
    __syncthreads();
    for (int off = 1; off < 1024; off <<= 1) {
        int v = (t >= off) ? s[t - off] : 0;
        __syncthreads();
        s[t] += v;
        __syncthreads();
    }
    int run = s[t] - sum;  // exclusive
    for (int i = 0; i < 49; ++i) {
        int idx = base + i;
        if (idx < N_NODES) {
            rowoff[idx] = run;
            wp[idx] = run;
            run += deg[idx];
        }
    }
    if (t == 0) rowoff[N_NODES] = N_EDGES;
}

__global__ __launch_bounds__(256) void k_scatter(const int* __restrict__ src, const int* __restrict__ dst,
                                                 int* __restrict__ wp, int* __restrict__ csr_src) {
    int i = blockIdx.x * 256 + threadIdx.x;
    if (i < N_EDGES) {
        int p = atomicAdd(&wp[dst[i]], 1);
        csr_src[p] = src[i];
    }
}

// ---------------- fused weight transpose + bf16: W1, W2, resW2 ----------------
// bx<8: W1 (256x256) -> W1T[n][k]; bx==8: W2 (256x32) -> W2T[0:32]; bx==9: resW2 -> W2T[32:64]

__global__ __launch_bounds__(256) void k_trans(const float* __restrict__ W1, const float* __restrict__ W2,
                                               const float* __restrict__ resW2,
                                               unsigned short* __restrict__ W1T, unsigned short* __restrict__ W2T) {
    __shared__ unsigned short tile[32][33];
    int bx = blockIdx.x;
    const float* in;
    unsigned short* out;
    int Nn, n0;
    if (bx < 8)      { in = W1;    out = W1T;            Nn = 256; n0 = bx * 32; }
    else if (bx == 8){ in = W2;    out = W2T;            Nn = 32;  n0 = 0; }
    else             { in = resW2; out = W2T + 32 * 256; Nn = 32;  n0 = 0; }
    int k0 = blockIdx.y * 32;
    int tx = threadIdx.x & 31, ty = threadIdx.x >> 5;  // 32 x 8
    #pragma unroll
    for (int r = 0; r < 4; ++r) {
        int k = k0 + ty + r * 8;
        tile[ty + r * 8][tx] = f2bf(in[(size_t)k * Nn + n0 + tx]);
    }
    __syncthreads();
    #pragma unroll
    for (int r = 0; r < 4; ++r) {
        int n = ty + r * 8;
        out[(size_t)(n0 + n) * 256 + k0 + tx] = tile[tx][n];
    }
}

// ---------------- GEMM1 + fused elr1 ----------------
// feat1b = bf16(x @ W1); el1/er1 computed from fp32 acc in epilogue.
// A: x f32, cast in-register, LDS stride 36 shorts. B: W1T bf16 via global_load_lds (stride 32).

#define LDA_A 36

__global__ __launch_bounds__(256) void k_gemm1f(const float* __restrict__ x,
                                                const unsigned short* __restrict__ BT,
                                                const float* __restrict__ al1, const float* __restrict__ ar1,
                                                unsigned short* __restrict__ Cb,
                                                float* __restrict__ el1, float* __restrict__ er1) {
    __shared__ unsigned short As[128 * LDA_A];
    __shared__ unsigned short Bs[128 * 32];
    const int t = threadIdx.x;
    const int bm0 = blockIdx.x * 128;
    const int bn0 = blockIdx.y * 128;
    const int wave = t >> 6, lane = t & 63;
    const int wm = (wave & 1) * 64, wn = (wave >> 1) * 64;
    const int lm = lane & 15, quad = lane >> 4;
    const int lrow = lane >> 2;          // 0..15
    const int lchk = (lane & 3) * 8;     // short offset

    f32x4 acc[4][4];
    #pragma unroll
    for (int i = 0; i < 4; ++i)
        #pragma unroll
        for (int j = 0; j < 4; ++j)
            #pragma unroll
            for (int r = 0; r < 4; ++r) acc[i][j][r] = 0.f;

    for (int k0 = 0; k0 < 256; k0 += 32) {
        // B tile async: 128 rows x 32 k
        #pragma unroll
        for (int i = 0; i < 2; ++i) {
            int r0 = wave * 32 + i * 16;
            gload_lds16(BT + (size_t)(bn0 + r0 + lrow) * 256 + k0 + lchk, &Bs[r0 * 32]);
        }
        // A tile: 128 rows x 32 f32 -> bf16, 4 float4/thread
        #pragma unroll
        for (int l = 0; l < 4; ++l) {
            int f = t + l * 256;
            int row = f >> 3;
            int q = f & 7;
            float4 v = make_float4(0.f, 0.f, 0.f, 0.f);
            if (bm0 + row < N_NODES)
                v = *(const float4*)(x + (size_t)(bm0 + row) * 256 + k0 + q * 4);
            ushort4 h;
            h.x = f2bf(v.x); h.y = f2bf(v.y); h.z = f2bf(v.z); h.w = f2bf(v.w);
            *(ushort4*)(&As[row * LDA_A + q * 4]) = h;
        }
        __syncthreads();
        bf16x8 af[4], bfr[4];
        #pragma unroll
        for (int i = 0; i < 4; ++i)
            af[i] = *(const bf16x8*)(&As[(wm + i * 16 + lm) * LDA_A + quad * 8]);
        #pragma unroll
        for (int i = 0; i < 4; ++i)
            bfr[i] = *(const bf16x8*)(&Bs[(wn + i * 16 + lm) * 32 + quad * 8]);
        #pragma unroll
        for (int mi = 0; mi < 4; ++mi)
            #pragma unroll
            for (int ni = 0; ni < 4; ++ni)
                acc[mi][ni] = __builtin_amdgcn_mfma_f32_16x16x32_bf16(af[mi], bfr[ni], acc[mi][ni], 0, 0, 0);
        __syncthreads();
    }
    // store feat1b (C/D layout: col=lane&15 group, row=quad*4+r)
    #pragma unroll
    for (int mi = 0; mi < 4; ++mi) {
        #pragma unroll
        for (int ni = 0; ni < 4; ++ni) {
            int col = bn0 + wn + ni * 16 + lm;
            #pragma unroll
            for (int r = 0; r < 4; ++r) {
                int row = bm0 + wm + mi * 16 + quad * 4 + r;
                if (row < N_NODES)
                    Cb[(size_t)row * 256 + col] = f2bf(acc[mi][ni][r]);
            }
        }
    }
    // fused elr1: wave's 64 cols = 2 heads (32 cols each)
    float alv[4], arv[4];
    #pragma unroll
    for (int ni = 0; ni < 4; ++ni) {
        int colg = bn0 + wn + ni * 16 + lm;
        alv[ni] = al1[colg];
        arv[ni] = ar1[colg];
    }
    int head0 = (bn0 + wn) >> 5;
    #pragma unroll
    for (int g = 0; g < 2; ++g) {
        #pragma unroll
        for (int mi = 0; mi < 4; ++mi) {
            #pragma unroll
            for (int r = 0; r < 4; ++r) {
                float pel = acc[mi][2 * g][r] * alv[2 * g] + acc[mi][2 * g + 1][r] * alv[2 * g + 1];
                float per = acc[mi][2 * g][r] * arv[2 * g] + acc[mi][2 * g + 1][r] * arv[2 * g + 1];
                #pragma unroll
                for (int m = 1; m <= 8; m <<= 1) {
                    pel += __shfl_xor(pel, m, 64);
                    per += __shfl_xor(per, m, 64);
                }
                if (lm == 0) {
                    int row = bm0 + wm + mi * 16 + quad * 4 + r;
                    if (row < N_NODES) {
                        el1[row * 8 + head0 + g] = pel;
                        er1[row * 8 + head0 + g] = per;
                    }
                }
            }
        }
    }
}

// ---------------- L1 aggregation: one wave per dst node (R2 form, 4-edge unroll) ----------------

__global__ __launch_bounds__(256) void k_agg1(const unsigned short* __restrict__ feat1b,
                                              const float* __restrict__ el1, const float* __restrict__ er1,
                                              const float* __restrict__ x, const float* __restrict__ b1,
                                              const int* __restrict__ rowoff, const int* __restrict__ csr_src,
                                              unsigned short* __restrict__ y_b) {
    int v = (blockIdx.x * 256 + threadIdx.x) >> 6;
    int lane = threadIdx.x & 63;
    if (v >= N_NODES) return;
    int h = lane >> 3;
    float er = er1[v * 8 + h];
    int c0 = lane * 4;
    float ax = 0.f, ay = 0.f, az = 0.f, aw = 0.f, wsum = 0.f;
    int s = rowoff[v], e = rowoff[v + 1];
    int j = s;
    for (; j + 3 < e; j += 4) {
        int u0 = csr_src[j], u1 = csr_src[j + 1], u2 = csr_src[j + 2], u3 = csr_src[j + 3];
        float t0 = el1[u0 * 8 + h] + er;
        float t1 = el1[u1 * 8 + h] + er;
        float t2 = el1[u2 * 8 + h] + er;
        float t3 = el1[u3 * 8 + h] + er;
        ushort4 h0 = *(const ushort4*)(feat1b + (size_t)u0 * 256 + c0);
        ushort4 h1 = *(const ushort4*)(feat1b + (size_t)u1 * 256 + c0);
        ushort4 h2 = *(const ushort4*)(feat1b + (size_t)u2 * 256 + c0);
        ushort4 h3 = *(const ushort4*)(feat1b + (size_t)u3 * 256 + c0);
        t0 = t0 > 0.f ? t0 : NEG_SLOPE * t0;
        t1 = t1 > 0.f ? t1 : NEG_SLOPE * t1;
        t2 = t2 > 0.f ? t2 : NEG_SLOPE * t2;
        t3 = t3 > 0.f ? t3 : NEG_SLOPE * t3;
        float w0 = __expf(t0), w1 = __expf(t1), w2 = __expf(t2), w3 = __expf(t3);
        wsum += (w0 + w1) + (w2 + w3);
        ax += w0 * bf2f(h0.x) + w1 * bf2f(h1.x) + w2 * bf2f(h2.x) + w3 * bf2f(h3.x);
        ay += w0 * bf2f(h0.y) + w1 * bf2f(h1.y) + w2 * bf2f(h2.y) + w3 * bf2f(h3.y);
        az += w0 * bf2f(h0.z) + w1 * bf2f(h1.z) + w2 * bf2f(h2.z) + w3 * bf2f(h3.z);
        aw += w0 * bf2f(h0.w) + w1 * bf2f(h1.w) + w2 * bf2f(h2.w) + w3 * bf2f(h3.w);
    }
    for (; j < e; ++j) {
        int u = csr_src[j];
        float t = el1[u * 8 + h] + er;
        ushort4 hh = *(const ushort4*)(feat1b + (size_t)u * 256 + c0);
        t = t > 0.f ? t : NEG_SLOPE * t;
        float w = __expf(t);
        wsum += w;
        ax += w * bf2f(hh.x);
        ay += w * bf2f(hh.y);
        az += w * bf2f(hh.z);
        aw += w * bf2f(hh.w);
    }
    float inv = (e > s) ? 1.f / wsum : 0.f;
    float4 r = *(const float4*)(x + (size_t)v * 256 + c0);
    float4 bb = *(const float4*)(b1 + c0);
    ushort4 o;
    o.x = f2bf(fmaxf(ax * inv + r.x + bb.x, 0.f));
    o.y = f2bf(fmaxf(ay * inv + r.y + bb.y, 0.f));
    o.z = f2bf(fmaxf(az * inv + r.z + bb.z, 0.f));
    o.w = f2bf(fmaxf(aw * inv + r.w + bb.w, 0.f));
    *(ushort4*)(y_b + (size_t)v * 256 + c0) = o;
}

// ---------------- GEMM2 + fused elr2: [feat2b|res2] = y_b @ [W2|resW2] ----------------

__global__ __launch_bounds__(256) void k_gemm2f(const unsigned short* __restrict__ Ab,
                                                const unsigned short* __restrict__ BT,  // [64][256]
                                                const float* __restrict__ al2, const float* __restrict__ ar2,
                                                unsigned short* __restrict__ feat2b, float* __restrict__ res2,
                                                float* __restrict__ el2, float* __restrict__ er2) {
    __shared__ unsigned short As[128 * 32];
    __shared__ unsigned short Bs[64 * 32];
    const int t = threadIdx.x;
    const int bm0 = blockIdx.x * 128;
    const int wave = t >> 6, lane = t & 63;
    const int wm = (wave & 1) * 64, wn = (wave >> 1) * 32;
    const int lm = lane & 15, quad = lane >> 4;
    const int lrow = lane >> 2;
    const int lchk = (lane & 3) * 8;

    f32x4 acc[4][2];
    #pragma unroll
    for (int i = 0; i < 4; ++i)
        #pragma unroll
        for (int j = 0; j < 2; ++j)
            #pragma unroll
            for (int r = 0; r < 4; ++r) acc[i][j][r] = 0.f;

    for (int k0 = 0; k0 < 256; k0 += 32) {
        #pragma unroll
        for (int i = 0; i < 2; ++i) {
            int r0 = wave * 32 + i * 16;
            gload_lds16(Ab + (size_t)(bm0 + r0 + lrow) * 256 + k0 + lchk, &As[r0 * 32]);
        }
        {
            int r0 = wave * 16;
            gload_lds16(BT + (size_t)(r0 + lrow) * 256 + k0 + lchk, &Bs[r0 * 32]);
        }
        __syncthreads();
        bf16x8 af[4], bfr[2];
        #pragma unroll
        for (int i = 0; i < 4; ++i)
            af[i] = *(const bf16x8*)(&As[(wm + i * 16 + lm) * 32 + quad * 8]);
        #pragma unroll
        for (int i = 0; i < 2; ++i)
            bfr[i] = *(const bf16x8*)(&Bs[(wn + i * 16 + lm) * 32 + quad * 8]);
        #pragma unroll
        for (int mi = 0; mi < 4; ++mi)
            #pragma unroll
            for (int ni = 0; ni < 2; ++ni)
                acc[mi][ni] = __builtin_amdgcn_mfma_f32_16x16x32_bf16(af[mi], bfr[ni], acc[mi][ni], 0, 0, 0);
        __syncthreads();
    }
    #pragma unroll
    for (int mi = 0; mi < 4; ++mi) {
        #pragma unroll
        for (int ni = 0; ni < 2; ++ni) {
            int col = wn + ni * 16 + lm;  // 0..63
            #pragma unroll
            for (int r = 0; r < 4; ++r) {
                int row = bm0 + wm + mi * 16 + quad * 4 + r;
                if (row < N_NODES) {
                    float val = acc[mi][ni][r];
                    if (col < 32) feat2b[(size_t)row * 32 + col] = f2bf(val);
                    else          res2[(size_t)row * 32 + col - 32] = val;
                }
            }
        }
    }
    // fused elr2: only waves covering cols 0..31
    if (wn == 0) {
        float alv[2], arv[2];
        #pragma unroll
        for (int ni = 0; ni < 2; ++ni) {
            alv[ni] = al2[ni * 16 + lm];
            arv[ni] = ar2[ni * 16 + lm];
        }
        #pragma unroll
        for (int mi = 0; mi < 4; ++mi) {
            #pragma unroll
            for (int r = 0; r < 4; ++r) {
                float pel = acc[mi][0][r] * alv[0] + acc[mi][1][r] * alv[1];
                float per = acc[mi][0][r] * arv[0] + acc[mi][1][r] * arv[1];
                #pragma unroll
                for (int m = 1; m <= 8; m <<= 1) {
                    pel += __shfl_xor(pel, m, 64);
                    per += __shfl_xor(per, m, 64);
                }
                if (lm == 0) {
                    int row = bm0 + wm + mi * 16 + quad * 4 + r;
                    if (row < N_NODES) {
                        el2[row] = pel;
                        er2[row] = per;
                    }
                }
            }
        }
    }
}

// ---------------- L2 aggregation: 32 lanes per dst node, inline exp, bf16 feat2 ----------------

__global__ __launch_bounds__(256) void k_agg2(const unsigned short* __restrict__ feat2b,
                                              const float* __restrict__ el2, const float* __restrict__ er2,
                                              const float* __restrict__ res2, const float* __restrict__ b2,
                                              const int* __restrict__ rowoff, const int* __restrict__ csr_src,
                                              float* __restrict__ out) {
    int g = blockIdx.x * 256 + threadIdx.x;
    int v = g >> 5;
    int c = g & 31;
    if (v >= N_NODES) return;
    float er = er2[v];
    float acc = 0.f, wsum = 0.f;
    int s = rowoff[v], e = rowoff[v + 1];
    int j = s;
    for (; j + 1 < e; j += 2) {
        int u0 = csr_src[j], u1 = csr_src[j + 1];
        float t0 = el2[u0] + er;
        float t1 = el2[u1] + er;
        float f0 = bf2f(feat2b[(size_t)u0 * 32 + c]);
        float f1 = bf2f(feat2b[(size_t)u1 * 32 + c]);
        t0 = t0 > 0.f ? t0 : NEG_SLOPE * t0;
        t1 = t1 > 0.f ? t1 : NEG_SLOPE * t1;
        float w0 = __expf(t0), w1 = __expf(t1);
        wsum += w0 + w1;
        acc += w0 * f0 + w1 * f1;
    }
    if (j < e) {
        int u = csr_src[j];
        float t = el2[u] + er;
        t = t > 0.f ? t : NEG_SLOPE * t;
        float w = __expf(t);
        wsum += w;
        acc += w * bf2f(feat2b[(size_t)u * 32 + c]);
    }
    float inv = (e > s) ? 1.f / wsum : 0.f;
    out[(size_t)v * 32 + c] = acc * inv + res2[(size_t)v * 32 + c] + b2[c];
}

// ---------------- launch ----------------

extern "C" void kernel_launch(void* const* d_in, const int* in_sizes, int n_in,
                              void* d_out, int out_size, void* d_ws, size_t ws_size,
                              hipStream_t stream) {
    const float* x     = (const float*)d_in[0];
    const int*   src   = (const int*)d_in[1];
    const int*   dst   = (const int*)d_in[2];
    const float* W1    = (const float*)d_in[3];
    const float* al1   = (const float*)d_in[4];
    const float* ar1   = (const float*)d_in[5];
    const float* b1    = (const float*)d_in[6];
    const float* W2    = (const float*)d_in[7];
    const float* al2   = (const float*)d_in[8];
    const float* ar2   = (const float*)d_in[9];
    const float* resW2 = (const float*)d_in[10];
    const float* b2    = (const float*)d_in[11];
    float* out = (float*)d_out;

    char* ws = (char*)d_ws;
    size_t off = 0;
    auto alloc = [&](size_t bytes) {
        void* p = ws + off;
        off += (bytes + 255) & ~(size_t)255;
        return p;
    };
    unsigned short* feat1b = (unsigned short*)alloc((size_t)N_NODES * 256 * 2);
    unsigned short* y_b    = (unsigned short*)alloc((size_t)M_PAD * 256 * 2);
    unsigned short* W1T    = (unsigned short*)alloc((size_t)256 * 256 * 2);
    unsigned short* W2T    = (unsigned short*)alloc((size_t)64 * 256 * 2);
    unsigned short* feat2b = (unsigned short*)alloc((size_t)N_NODES * 32 * 2);
    float* res2   = (float*)alloc((size_t)N_NODES * 32 * 4);
    float* el1    = (float*)alloc((size_t)N_NODES * 8 * 4);
    float* er1    = (float*)alloc((size_t)N_NODES * 8 * 4);
    float* el2    = (float*)alloc((size_t)N_NODES * 4);
    float* er2    = (float*)alloc((size_t)N_NODES * 4);
    int*   deg    = (int*)alloc((size_t)N_NODES * 4);
    int*   rowoff = (int*)alloc((size_t)(N_NODES + 1) * 4);
    int*   wp     = (int*)alloc((size_t)N_NODES * 4);
    int*   csr    = (int*)alloc((size_t)N_EDGES * 4);
    (void)ws_size;

    // CSR build (rebuilt every call)
    hipMemsetAsync(deg, 0, (size_t)N_NODES * 4, stream);
    k_hist<<<(N_EDGES + 255) / 256, 256, 0, stream>>>(dst, deg);
    k_scan<<<1, 1024, 0, stream>>>(deg, rowoff, wp);
    k_scatter<<<(N_EDGES + 255) / 256, 256, 0, stream>>>(src, dst, wp, csr);

    // weights
    k_trans<<<dim3(10, 8), 256, 0, stream>>>(W1, W2, resW2, W1T, W2T);

    // Layer 1
    k_gemm1f<<<dim3(M_PAD / 128, 2), 256, 0, stream>>>(x, W1T, al1, ar1, feat1b, el1, er1);
    k_agg1<<<(N_NODES * 64) / 256, 256, 0, stream>>>(feat1b, el1, er1, x, b1, rowoff, csr, y_b);

    // Layer 2
    k_gemm2f<<<M_PAD / 128, 256, 0, stream>>>(y_b, W2T, al2, ar2, feat2b, res2, el2, er2);
    k_agg2<<<(N_NODES * 32) / 256, 256, 0, stream>>>(feat2b, el2, er2, res2, b2, rowoff, csr, out);
}

// Round 5
// 369.009 us; speedup vs baseline: 1.3731x; 1.3059x over previous
//
#include <hip/hip_runtime.h>
#include <hip/hip_bf16.h>

#define N_NODES 50000
#define M_PAD   50048          // 391 * 128
#define N_EDGES 800000
#define NEG_SLOPE 0.2f

#define SCAN_BLK 512
#define SCAN_NB ((N_NODES + SCAN_BLK - 1) / SCAN_BLK)   // 98

typedef __attribute__((ext_vector_type(8))) short bf16x8;
typedef __attribute__((ext_vector_type(4))) float f32x4;

__device__ __forceinline__ unsigned short f2bf(float f) {
    unsigned u = __float_as_uint(f);
    u += 0x7FFFu + ((u >> 16) & 1u);          // RNE
    return (unsigned short)(u >> 16);
}
__device__ __forceinline__ float bf2f(unsigned short h) {
    return __uint_as_float(((unsigned)h) << 16);
}

// async global->LDS, 16B per lane; LDS dest = wave-uniform base + lane*16
__device__ __forceinline__ void gload_lds16(const void* g, void* l) {
    __builtin_amdgcn_global_load_lds(
        (const __attribute__((address_space(1))) unsigned int*)g,
        (__attribute__((address_space(3))) unsigned int*)l,
        16, 0, 0);
}

// ---------------- CSR build ----------------

__global__ __launch_bounds__(256) void k_hist(const int* __restrict__ dst, int* __restrict__ deg) {
    int i = blockIdx.x * 256 + threadIdx.x;
    if (i < N_EDGES) atomicAdd(&deg[dst[i]], 1);
}

__global__ __launch_bounds__(SCAN_BLK) void k_scan1(const int* __restrict__ deg,
                                                    int* __restrict__ rowoff,
                                                    int* __restrict__ bsum) {
    __shared__ int s[SCAN_BLK];
    int i = blockIdx.x * SCAN_BLK + threadIdx.x;
    int v = (i < N_NODES) ? deg[i] : 0;
    s[threadIdx.x] = v;
    __syncthreads();
    for (int off = 1; off < SCAN_BLK; off <<= 1) {
        int t = (threadIdx.x >= off) ? s[threadIdx.x - off] : 0;
        __syncthreads();
        s[threadIdx.x] += t;
        __syncthreads();
    }
    if (i < N_NODES) rowoff[i] = s[threadIdx.x];
    if (threadIdx.x == SCAN_BLK - 1) bsum[blockIdx.x] = s[SCAN_BLK - 1];
}

__global__ __launch_bounds__(128) void k_scan2(int* __restrict__ bsum) {
    __shared__ int s[128];
    int t = threadIdx.x;
    int v = (t < SCAN_NB) ? bsum[t] : 0;
    s[t] = v;
    __syncthreads();
    for (int off = 1; off < 128; off <<= 1) {
        int x = (t >= off) ? s[t - off] : 0;
        __syncthreads();
        s[t] += x;
        __syncthreads();
    }
    if (t < SCAN_NB) bsum[t] = s[t] - v;  // exclusive
}

__global__ __launch_bounds__(SCAN_BLK) void k_scan3(const int* __restrict__ deg,
                                                    int* __restrict__ rowoff,
                                                    int* __restrict__ wp,
                                                    const int* __restrict__ bsum) {
    int i = blockIdx.x * SCAN_BLK + threadIdx.x;
    if (i < N_NODES) {
        int excl = rowoff[i] - deg[i] + bsum[blockIdx.x];
        rowoff[i] = excl;
        wp[i] = excl;
    }
    if (i == 0) rowoff[N_NODES] = N_EDGES;
}

__global__ __launch_bounds__(256) void k_scatter(const int* __restrict__ src, const int* __restrict__ dst,
                                                 int* __restrict__ wp, int* __restrict__ csr_src) {
    int i = blockIdx.x * 256 + threadIdx.x;
    if (i < N_EDGES) {
        int p = atomicAdd(&wp[dst[i]], 1);
        csr_src[p] = src[i];
    }
}

// ---------------- fused weight transpose + bf16: W1, W2, resW2 ----------------
// bx<8: W1 (256x256) -> W1T[n][k]; bx==8: W2 (256x32) -> W2T[0:32]; bx==9: resW2 -> W2T[32:64]

__global__ __launch_bounds__(256) void k_trans(const float* __restrict__ W1, const float* __restrict__ W2,
                                               const float* __restrict__ resW2,
                                               unsigned short* __restrict__ W1T, unsigned short* __restrict__ W2T) {
    __shared__ unsigned short tile[32][33];
    int bx = blockIdx.x;
    const float* in;
    unsigned short* out;
    int Nn, n0;
    if (bx < 8)      { in = W1;    out = W1T;            Nn = 256; n0 = bx * 32; }
    else if (bx == 8){ in = W2;    out = W2T;            Nn = 32;  n0 = 0; }
    else             { in = resW2; out = W2T + 32 * 256; Nn = 32;  n0 = 0; }
    int k0 = blockIdx.y * 32;
    int tx = threadIdx.x & 31, ty = threadIdx.x >> 5;  // 32 x 8
    #pragma unroll
    for (int r = 0; r < 4; ++r) {
        int k = k0 + ty + r * 8;
        tile[ty + r * 8][tx] = f2bf(in[(size_t)k * Nn + n0 + tx]);
    }
    __syncthreads();
    #pragma unroll
    for (int r = 0; r < 4; ++r) {
        int n = ty + r * 8;
        out[(size_t)(n0 + n) * 256 + k0 + tx] = tile[tx][n];
    }
}

// ---------------- GEMM1 + fused elr1 ----------------
// feat1b = bf16(x @ W1); el1/er1 computed from fp32 acc in epilogue.
// A: x f32, cast in-register, LDS stride 36 shorts. B: W1T bf16 via global_load_lds (stride 32).

#define LDA_A 36

__global__ __launch_bounds__(256) void k_gemm1f(const float* __restrict__ x,
                                                const unsigned short* __restrict__ BT,
                                                const float* __restrict__ al1, const float* __restrict__ ar1,
                                                unsigned short* __restrict__ Cb,
                                                float* __restrict__ el1, float* __restrict__ er1) {
    __shared__ unsigned short As[128 * LDA_A];
    __shared__ unsigned short Bs[128 * 32];
    const int t = threadIdx.x;
    const int bm0 = blockIdx.x * 128;
    const int bn0 = blockIdx.y * 128;
    const int wave = t >> 6, lane = t & 63;
    const int wm = (wave & 1) * 64, wn = (wave >> 1) * 64;
    const int lm = lane & 15, quad = lane >> 4;
    const int lrow = lane >> 2;          // 0..15
    const int lchk = (lane & 3) * 8;     // short offset

    f32x4 acc[4][4];
    #pragma unroll
    for (int i = 0; i < 4; ++i)
        #pragma unroll
        for (int j = 0; j < 4; ++j)
            #pragma unroll
            for (int r = 0; r < 4; ++r) acc[i][j][r] = 0.f;

    for (int k0 = 0; k0 < 256; k0 += 32) {
        // B tile async: 128 rows x 32 k
        #pragma unroll
        for (int i = 0; i < 2; ++i) {
            int r0 = wave * 32 + i * 16;
            gload_lds16(BT + (size_t)(bn0 + r0 + lrow) * 256 + k0 + lchk, &Bs[r0 * 32]);
        }
        // A tile: 128 rows x 32 f32 -> bf16, 4 float4/thread
        #pragma unroll
        for (int l = 0; l < 4; ++l) {
            int f = t + l * 256;
            int row = f >> 3;
            int q = f & 7;
            float4 v = make_float4(0.f, 0.f, 0.f, 0.f);
            if (bm0 + row < N_NODES)
                v = *(const float4*)(x + (size_t)(bm0 + row) * 256 + k0 + q * 4);
            ushort4 h;
            h.x = f2bf(v.x); h.y = f2bf(v.y); h.z = f2bf(v.z); h.w = f2bf(v.w);
            *(ushort4*)(&As[row * LDA_A + q * 4]) = h;
        }
        __syncthreads();
        bf16x8 af[4], bfr[4];
        #pragma unroll
        for (int i = 0; i < 4; ++i)
            af[i] = *(const bf16x8*)(&As[(wm + i * 16 + lm) * LDA_A + quad * 8]);
        #pragma unroll
        for (int i = 0; i < 4; ++i)
            bfr[i] = *(const bf16x8*)(&Bs[(wn + i * 16 + lm) * 32 + quad * 8]);
        #pragma unroll
        for (int mi = 0; mi < 4; ++mi)
            #pragma unroll
            for (int ni = 0; ni < 4; ++ni)
                acc[mi][ni] = __builtin_amdgcn_mfma_f32_16x16x32_bf16(af[mi], bfr[ni], acc[mi][ni], 0, 0, 0);
        __syncthreads();
    }
    // store feat1b (C/D layout: col=lane&15 group, row=quad*4+r)
    #pragma unroll
    for (int mi = 0; mi < 4; ++mi) {
        #pragma unroll
        for (int ni = 0; ni < 4; ++ni) {
            int col = bn0 + wn + ni * 16 + lm;
            #pragma unroll
            for (int r = 0; r < 4; ++r) {
                int row = bm0 + wm + mi * 16 + quad * 4 + r;
                if (row < N_NODES)
                    Cb[(size_t)row * 256 + col] = f2bf(acc[mi][ni][r]);
            }
        }
    }
    // fused elr1: wave's 64 cols = 2 heads (32 cols each)
    float alv[4], arv[4];
    #pragma unroll
    for (int ni = 0; ni < 4; ++ni) {
        int colg = bn0 + wn + ni * 16 + lm;
        alv[ni] = al1[colg];
        arv[ni] = ar1[colg];
    }
    int head0 = (bn0 + wn) >> 5;
    #pragma unroll
    for (int g = 0; g < 2; ++g) {
        #pragma unroll
        for (int mi = 0; mi < 4; ++mi) {
            #pragma unroll
            for (int r = 0; r < 4; ++r) {
                float pel = acc[mi][2 * g][r] * alv[2 * g] + acc[mi][2 * g + 1][r] * alv[2 * g + 1];
                float per = acc[mi][2 * g][r] * arv[2 * g] + acc[mi][2 * g + 1][r] * arv[2 * g + 1];
                #pragma unroll
                for (int m = 1; m <= 8; m <<= 1) {
                    pel += __shfl_xor(pel, m, 64);
                    per += __shfl_xor(per, m, 64);
                }
                if (lm == 0) {
                    int row = bm0 + wm + mi * 16 + quad * 4 + r;
                    if (row < N_NODES) {
                        el1[row * 8 + head0 + g] = pel;
                        er1[row * 8 + head0 + g] = per;
                    }
                }
            }
        }
    }
}

// ---------------- L1 aggregation: one wave per dst node (4-edge unroll) ----------------

__global__ __launch_bounds__(256) void k_agg1(const unsigned short* __restrict__ feat1b,
                                              const float* __restrict__ el1, const float* __restrict__ er1,
                                              const float* __restrict__ x, const float* __restrict__ b1,
                                              const int* __restrict__ rowoff, const int* __restrict__ csr_src,
                                              unsigned short* __restrict__ y_b) {
    int v = (blockIdx.x * 256 + threadIdx.x) >> 6;
    int lane = threadIdx.x & 63;
    if (v >= N_NODES) return;
    int h = lane >> 3;
    float er = er1[v * 8 + h];
    int c0 = lane * 4;
    float ax = 0.f, ay = 0.f, az = 0.f, aw = 0.f, wsum = 0.f;
    int s = rowoff[v], e = rowoff[v + 1];
    int j = s;
    for (; j + 3 < e; j += 4) {
        int u0 = csr_src[j], u1 = csr_src[j + 1], u2 = csr_src[j + 2], u3 = csr_src[j + 3];
        float t0 = el1[u0 * 8 + h] + er;
        float t1 = el1[u1 * 8 + h] + er;
        float t2 = el1[u2 * 8 + h] + er;
        float t3 = el1[u3 * 8 + h] + er;
        ushort4 h0 = *(const ushort4*)(feat1b + (size_t)u0 * 256 + c0);
        ushort4 h1 = *(const ushort4*)(feat1b + (size_t)u1 * 256 + c0);
        ushort4 h2 = *(const ushort4*)(feat1b + (size_t)u2 * 256 + c0);
        ushort4 h3 = *(const ushort4*)(feat1b + (size_t)u3 * 256 + c0);
        t0 = t0 > 0.f ? t0 : NEG_SLOPE * t0;
        t1 = t1 > 0.f ? t1 : NEG_SLOPE * t1;
        t2 = t2 > 0.f ? t2 : NEG_SLOPE * t2;
        t3 = t3 > 0.f ? t3 : NEG_SLOPE * t3;
        float w0 = __expf(t0), w1 = __expf(t1), w2 = __expf(t2), w3 = __expf(t3);
        wsum += (w0 + w1) + (w2 + w3);
        ax += w0 * bf2f(h0.x) + w1 * bf2f(h1.x) + w2 * bf2f(h2.x) + w3 * bf2f(h3.x);
        ay += w0 * bf2f(h0.y) + w1 * bf2f(h1.y) + w2 * bf2f(h2.y) + w3 * bf2f(h3.y);
        az += w0 * bf2f(h0.z) + w1 * bf2f(h1.z) + w2 * bf2f(h2.z) + w3 * bf2f(h3.z);
        aw += w0 * bf2f(h0.w) + w1 * bf2f(h1.w) + w2 * bf2f(h2.w) + w3 * bf2f(h3.w);
    }
    for (; j < e; ++j) {
        int u = csr_src[j];
        float t = el1[u * 8 + h] + er;
        ushort4 hh = *(const ushort4*)(feat1b + (size_t)u * 256 + c0);
        t = t > 0.f ? t : NEG_SLOPE * t;
        float w = __expf(t);
        wsum += w;
        ax += w * bf2f(hh.x);
        ay += w * bf2f(hh.y);
        az += w * bf2f(hh.z);
        aw += w * bf2f(hh.w);
    }
    float inv = (e > s) ? 1.f / wsum : 0.f;
    float4 r = *(const float4*)(x + (size_t)v * 256 + c0);
    float4 bb = *(const float4*)(b1 + c0);
    ushort4 o;
    o.x = f2bf(fmaxf(ax * inv + r.x + bb.x, 0.f));
    o.y = f2bf(fmaxf(ay * inv + r.y + bb.y, 0.f));
    o.z = f2bf(fmaxf(az * inv + r.z + bb.z, 0.f));
    o.w = f2bf(fmaxf(aw * inv + r.w + bb.w, 0.f));
    *(ushort4*)(y_b + (size_t)v * 256 + c0) = o;
}

// ---------------- GEMM2 + fused elr2: [feat2b|res2] = y_b @ [W2|resW2] ----------------

__global__ __launch_bounds__(256) void k_gemm2f(const unsigned short* __restrict__ Ab,
                                                const unsigned short* __restrict__ BT,  // [64][256]
                                                const float* __restrict__ al2, const float* __restrict__ ar2,
                                                unsigned short* __restrict__ feat2b, float* __restrict__ res2,
                                                float* __restrict__ el2, float* __restrict__ er2) {
    __shared__ unsigned short As[128 * 32];
    __shared__ unsigned short Bs[64 * 32];
    const int t = threadIdx.x;
    const int bm0 = blockIdx.x * 128;
    const int wave = t >> 6, lane = t & 63;
    const int wm = (wave & 1) * 64, wn = (wave >> 1) * 32;
    const int lm = lane & 15, quad = lane >> 4;
    const int lrow = lane >> 2;
    const int lchk = (lane & 3) * 8;

    f32x4 acc[4][2];
    #pragma unroll
    for (int i = 0; i < 4; ++i)
        #pragma unroll
        for (int j = 0; j < 2; ++j)
            #pragma unroll
            for (int r = 0; r < 4; ++r) acc[i][j][r] = 0.f;

    for (int k0 = 0; k0 < 256; k0 += 32) {
        #pragma unroll
        for (int i = 0; i < 2; ++i) {
            int r0 = wave * 32 + i * 16;
            gload_lds16(Ab + (size_t)(bm0 + r0 + lrow) * 256 + k0 + lchk, &As[r0 * 32]);
        }
        {
            int r0 = wave * 16;
            gload_lds16(BT + (size_t)(r0 + lrow) * 256 + k0 + lchk, &Bs[r0 * 32]);
        }
        __syncthreads();
        bf16x8 af[4], bfr[2];
        #pragma unroll
        for (int i = 0; i < 4; ++i)
            af[i] = *(const bf16x8*)(&As[(wm + i * 16 + lm) * 32 + quad * 8]);
        #pragma unroll
        for (int i = 0; i < 2; ++i)
            bfr[i] = *(const bf16x8*)(&Bs[(wn + i * 16 + lm) * 32 + quad * 8]);
        #pragma unroll
        for (int mi = 0; mi < 4; ++mi)
            #pragma unroll
            for (int ni = 0; ni < 2; ++ni)
                acc[mi][ni] = __builtin_amdgcn_mfma_f32_16x16x32_bf16(af[mi], bfr[ni], acc[mi][ni], 0, 0, 0);
        __syncthreads();
    }
    #pragma unroll
    for (int mi = 0; mi < 4; ++mi) {
        #pragma unroll
        for (int ni = 0; ni < 2; ++ni) {
            int col = wn + ni * 16 + lm;  // 0..63
            #pragma unroll
            for (int r = 0; r < 4; ++r) {
                int row = bm0 + wm + mi * 16 + quad * 4 + r;
                if (row < N_NODES) {
                    float val = acc[mi][ni][r];
                    if (col < 32) feat2b[(size_t)row * 32 + col] = f2bf(val);
                    else          res2[(size_t)row * 32 + col - 32] = val;
                }
            }
        }
    }
    // fused elr2: only waves covering cols 0..31
    if (wn == 0) {
        float alv[2], arv[2];
        #pragma unroll
        for (int ni = 0; ni < 2; ++ni) {
            alv[ni] = al2[ni * 16 + lm];
            arv[ni] = ar2[ni * 16 + lm];
        }
        #pragma unroll
        for (int mi = 0; mi < 4; ++mi) {
            #pragma unroll
            for (int r = 0; r < 4; ++r) {
                float pel = acc[mi][0][r] * alv[0] + acc[mi][1][r] * alv[1];
                float per = acc[mi][0][r] * arv[0] + acc[mi][1][r] * arv[1];
                #pragma unroll
                for (int m = 1; m <= 8; m <<= 1) {
                    pel += __shfl_xor(pel, m, 64);
                    per += __shfl_xor(per, m, 64);
                }
                if (lm == 0) {
                    int row = bm0 + wm + mi * 16 + quad * 4 + r;
                    if (row < N_NODES) {
                        el2[row] = pel;
                        er2[row] = per;
                    }
                }
            }
        }
    }
}

// ---------------- L2 aggregation: 32 lanes per dst node, inline exp, bf16 feat2 ----------------

__global__ __launch_bounds__(256) void k_agg2(const unsigned short* __restrict__ feat2b,
                                              const float* __restrict__ el2, const float* __restrict__ er2,
                                              const float* __restrict__ res2, const float* __restrict__ b2,
                                              const int* __restrict__ rowoff, const int* __restrict__ csr_src,
                                              float* __restrict__ out) {
    int g = blockIdx.x * 256 + threadIdx.x;
    int v = g >> 5;
    int c = g & 31;
    if (v >= N_NODES) return;
    float er = er2[v];
    float acc = 0.f, wsum = 0.f;
    int s = rowoff[v], e = rowoff[v + 1];
    int j = s;
    for (; j + 1 < e; j += 2) {
        int u0 = csr_src[j], u1 = csr_src[j + 1];
        float t0 = el2[u0] + er;
        float t1 = el2[u1] + er;
        float f0 = bf2f(feat2b[(size_t)u0 * 32 + c]);
        float f1 = bf2f(feat2b[(size_t)u1 * 32 + c]);
        t0 = t0 > 0.f ? t0 : NEG_SLOPE * t0;
        t1 = t1 > 0.f ? t1 : NEG_SLOPE * t1;
        float w0 = __expf(t0), w1 = __expf(t1);
        wsum += w0 + w1;
        acc += w0 * f0 + w1 * f1;
    }
    if (j < e) {
        int u = csr_src[j];
        float t = el2[u] + er;
        t = t > 0.f ? t : NEG_SLOPE * t;
        float w = __expf(t);
        wsum += w;
        acc += w * bf2f(feat2b[(size_t)u * 32 + c]);
    }
    float inv = (e > s) ? 1.f / wsum : 0.f;
    out[(size_t)v * 32 + c] = acc * inv + res2[(size_t)v * 32 + c] + b2[c];
}

// ---------------- launch ----------------

extern "C" void kernel_launch(void* const* d_in, const int* in_sizes, int n_in,
                              void* d_out, int out_size, void* d_ws, size_t ws_size,
                              hipStream_t stream) {
    const float* x     = (const float*)d_in[0];
    const int*   src   = (const int*)d_in[1];
    const int*   dst   = (const int*)d_in[2];
    const float* W1    = (const float*)d_in[3];
    const float* al1   = (const float*)d_in[4];
    const float* ar1   = (const float*)d_in[5];
    const float* b1    = (const float*)d_in[6];
    const float* W2    = (const float*)d_in[7];
    const float* al2   = (const float*)d_in[8];
    const float* ar2   = (const float*)d_in[9];
    const float* resW2 = (const float*)d_in[10];
    const float* b2    = (const float*)d_in[11];
    float* out = (float*)d_out;

    char* ws = (char*)d_ws;
    size_t off = 0;
    auto alloc = [&](size_t bytes) {
        void* p = ws + off;
        off += (bytes + 255) & ~(size_t)255;
        return p;
    };
    unsigned short* feat1b = (unsigned short*)alloc((size_t)N_NODES * 256 * 2);
    unsigned short* y_b    = (unsigned short*)alloc((size_t)M_PAD * 256 * 2);
    unsigned short* W1T    = (unsigned short*)alloc((size_t)256 * 256 * 2);
    unsigned short* W2T    = (unsigned short*)alloc((size_t)64 * 256 * 2);
    unsigned short* feat2b = (unsigned short*)alloc((size_t)N_NODES * 32 * 2);
    float* res2   = (float*)alloc((size_t)N_NODES * 32 * 4);
    float* el1    = (float*)alloc((size_t)N_NODES * 8 * 4);
    float* er1    = (float*)alloc((size_t)N_NODES * 8 * 4);
    float* el2    = (float*)alloc((size_t)N_NODES * 4);
    float* er2    = (float*)alloc((size_t)N_NODES * 4);
    int*   deg    = (int*)alloc((size_t)N_NODES * 4);
    int*   rowoff = (int*)alloc((size_t)(N_NODES + 1) * 4);
    int*   wp     = (int*)alloc((size_t)N_NODES * 4);
    int*   bsum   = (int*)alloc((size_t)SCAN_NB * 4);
    int*   csr    = (int*)alloc((size_t)N_EDGES * 4);
    (void)ws_size;

    // CSR build (rebuilt every call) — multi-block scan (R2 form; single-block scan was 125 us!)
    hipMemsetAsync(deg, 0, (size_t)N_NODES * 4, stream);
    k_hist<<<(N_EDGES + 255) / 256, 256, 0, stream>>>(dst, deg);
    k_scan1<<<SCAN_NB, SCAN_BLK, 0, stream>>>(deg, rowoff, bsum);
    k_scan2<<<1, 128, 0, stream>>>(bsum);
    k_scan3<<<SCAN_NB, SCAN_BLK, 0, stream>>>(deg, rowoff, wp, bsum);
    k_scatter<<<(N_EDGES + 255) / 256, 256, 0, stream>>>(src, dst, wp, csr);

    // weights
    k_trans<<<dim3(10, 8), 256, 0, stream>>>(W1, W2, resW2, W1T, W2T);

    // Layer 1
    k_gemm1f<<<dim3(M_PAD / 128, 2), 256, 0, stream>>>(x, W1T, al1, ar1, feat1b, el1, er1);
    k_agg1<<<(N_NODES * 64) / 256, 256, 0, stream>>>(feat1b, el1, er1, x, b1, rowoff, csr, y_b);

    // Layer 2
    k_gemm2f<<<M_PAD / 128, 256, 0, stream>>>(y_b, W2T, al2, ar2, feat2b, res2, el2, er2);
    k_agg2<<<(N_NODES * 32) / 256, 256, 0, stream>>>(feat2b, el2, er2, res2, b2, rowoff, csr, out);
}

// Round 6
// 350.932 us; speedup vs baseline: 1.4438x; 1.0515x over previous
//
#include <hip/hip_runtime.h>
#include <hip/hip_bf16.h>

#define N_NODES 50000
#define M_PAD   50048          // 391 * 128
#define N_EDGES 800000
#define NEG_SLOPE 0.2f

#define SCAN_BLK 512
#define SCAN_NB ((N_NODES + SCAN_BLK - 1) / SCAN_BLK)   // 98

typedef __attribute__((ext_vector_type(8))) short bf16x8;
typedef __attribute__((ext_vector_type(4))) float f32x4;

__device__ __forceinline__ unsigned short f2bf(float f) {
    unsigned u = __float_as_uint(f);
    u += 0x7FFFu + ((u >> 16) & 1u);          // RNE
    return (unsigned short)(u >> 16);
}
__device__ __forceinline__ float bf2f(unsigned short h) {
    return __uint_as_float(((unsigned)h) << 16);
}

// async global->LDS, 16B per lane; LDS dest = wave-uniform base + lane*16
__device__ __forceinline__ void gload_lds16(const void* g, void* l) {
    __builtin_amdgcn_global_load_lds(
        (const __attribute__((address_space(1))) unsigned int*)g,
        (__attribute__((address_space(3))) unsigned int*)l,
        16, 0, 0);
}

// ---------------- weights transpose + deg zero (first dispatch) ----------------
// bx<8: W1 (256x256) -> W1T[n][k]; bx==8: W2 -> W2T[0:32]; bx==9: resW2 -> W2T[32:64]
// Also zeroes deg[] (ws is re-poisoned before every call).

__global__ __launch_bounds__(256) void k_trans(const float* __restrict__ W1, const float* __restrict__ W2,
                                               const float* __restrict__ resW2,
                                               unsigned short* __restrict__ W1T, unsigned short* __restrict__ W2T,
                                               int* __restrict__ deg) {
    // deg zeroing: 80 blocks x 256 threads
    int gtid = (blockIdx.y * 10 + blockIdx.x) * 256 + threadIdx.x;
    for (int i = gtid; i < N_NODES; i += 10 * 8 * 256) deg[i] = 0;

    __shared__ unsigned short tile[32][33];
    int bx = blockIdx.x;
    const float* in;
    unsigned short* out;
    int Nn, n0;
    if (bx < 8)      { in = W1;    out = W1T;            Nn = 256; n0 = bx * 32; }
    else if (bx == 8){ in = W2;    out = W2T;            Nn = 32;  n0 = 0; }
    else             { in = resW2; out = W2T + 32 * 256; Nn = 32;  n0 = 0; }
    int k0 = blockIdx.y * 32;
    int tx = threadIdx.x & 31, ty = threadIdx.x >> 5;  // 32 x 8
    #pragma unroll
    for (int r = 0; r < 4; ++r) {
        int k = k0 + ty + r * 8;
        tile[ty + r * 8][tx] = f2bf(in[(size_t)k * Nn + n0 + tx]);
    }
    __syncthreads();
    #pragma unroll
    for (int r = 0; r < 4; ++r) {
        int n = ty + r * 8;
        out[(size_t)(n0 + n) * 256 + k0 + tx] = tile[tx][n];
    }
}

// ---------------- CSR build ----------------

__global__ __launch_bounds__(256) void k_hist(const int* __restrict__ dst, int* __restrict__ deg) {
    int i = blockIdx.x * 256 + threadIdx.x;
    if (i < N_EDGES) atomicAdd(&deg[dst[i]], 1);
}

__global__ __launch_bounds__(SCAN_BLK) void k_scan1(const int* __restrict__ deg,
                                                    int* __restrict__ rowoff,
                                                    int* __restrict__ bsum) {
    __shared__ int s[SCAN_BLK];
    int i = blockIdx.x * SCAN_BLK + threadIdx.x;
    int v = (i < N_NODES) ? deg[i] : 0;
    s[threadIdx.x] = v;
    __syncthreads();
    for (int off = 1; off < SCAN_BLK; off <<= 1) {
        int t = (threadIdx.x >= off) ? s[threadIdx.x - off] : 0;
        __syncthreads();
        s[threadIdx.x] += t;
        __syncthreads();
    }
    if (i < N_NODES) rowoff[i] = s[threadIdx.x];
    if (threadIdx.x == SCAN_BLK - 1) bsum[blockIdx.x] = s[SCAN_BLK - 1];
}

// scan3 with inlined block-offset reduction: off = sum(bsum[0..bx-1])
__global__ __launch_bounds__(SCAN_BLK) void k_scan3(const int* __restrict__ deg,
                                                    int* __restrict__ rowoff,
                                                    int* __restrict__ wp,
                                                    const int* __restrict__ bsum) {
    __shared__ int red[8];
    int t = threadIdx.x;
    int part = 0;
    for (int i = t; i < (int)blockIdx.x; i += SCAN_BLK) part += bsum[i];
    #pragma unroll
    for (int m = 1; m <= 32; m <<= 1) part += __shfl_xor(part, m, 64);
    if ((t & 63) == 0) red[t >> 6] = part;
    __syncthreads();
    if (t == 0) {
        int o = 0;
        #pragma unroll
        for (int w = 0; w < 8; ++w) o += red[w];
        red[0] = o;
    }
    __syncthreads();
    int off = red[0];
    int i = blockIdx.x * SCAN_BLK + t;
    if (i < N_NODES) {
        int excl = rowoff[i] - deg[i] + off;
        rowoff[i] = excl;
        wp[i] = excl;
    }
    if (i == 0) rowoff[N_NODES] = N_EDGES;
}

__global__ __launch_bounds__(256) void k_scatter(const int* __restrict__ src, const int* __restrict__ dst,
                                                 int* __restrict__ wp, int* __restrict__ csr_src) {
    int i = blockIdx.x * 256 + threadIdx.x;
    if (i < N_EDGES) {
        int p = atomicAdd(&wp[dst[i]], 1);
        csr_src[p] = src[i];
    }
}

// ---------------- GEMM1 + fused elr1 ----------------

#define LDA_A 36

__global__ __launch_bounds__(256) void k_gemm1f(const float* __restrict__ x,
                                                const unsigned short* __restrict__ BT,
                                                const float* __restrict__ al1, const float* __restrict__ ar1,
                                                unsigned short* __restrict__ Cb,
                                                float* __restrict__ el1, float* __restrict__ er1) {
    __shared__ unsigned short As[128 * LDA_A];
    __shared__ unsigned short Bs[128 * 32];
    const int t = threadIdx.x;
    const int bm0 = blockIdx.x * 128;
    const int bn0 = blockIdx.y * 128;
    const int wave = t >> 6, lane = t & 63;
    const int wm = (wave & 1) * 64, wn = (wave >> 1) * 64;
    const int lm = lane & 15, quad = lane >> 4;
    const int lrow = lane >> 2;          // 0..15
    const int lchk = (lane & 3) * 8;     // short offset

    f32x4 acc[4][4];
    #pragma unroll
    for (int i = 0; i < 4; ++i)
        #pragma unroll
        for (int j = 0; j < 4; ++j)
            #pragma unroll
            for (int r = 0; r < 4; ++r) acc[i][j][r] = 0.f;

    for (int k0 = 0; k0 < 256; k0 += 32) {
        #pragma unroll
        for (int i = 0; i < 2; ++i) {
            int r0 = wave * 32 + i * 16;
            gload_lds16(BT + (size_t)(bn0 + r0 + lrow) * 256 + k0 + lchk, &Bs[r0 * 32]);
        }
        #pragma unroll
        for (int l = 0; l < 4; ++l) {
            int f = t + l * 256;
            int row = f >> 3;
            int q = f & 7;
            float4 v = make_float4(0.f, 0.f, 0.f, 0.f);
            if (bm0 + row < N_NODES)
                v = *(const float4*)(x + (size_t)(bm0 + row) * 256 + k0 + q * 4);
            ushort4 h;
            h.x = f2bf(v.x); h.y = f2bf(v.y); h.z = f2bf(v.z); h.w = f2bf(v.w);
            *(ushort4*)(&As[row * LDA_A + q * 4]) = h;
        }
        __syncthreads();
        bf16x8 af[4], bfr[4];
        #pragma unroll
        for (int i = 0; i < 4; ++i)
            af[i] = *(const bf16x8*)(&As[(wm + i * 16 + lm) * LDA_A + quad * 8]);
        #pragma unroll
        for (int i = 0; i < 4; ++i)
            bfr[i] = *(const bf16x8*)(&Bs[(wn + i * 16 + lm) * 32 + quad * 8]);
        #pragma unroll
        for (int mi = 0; mi < 4; ++mi)
            #pragma unroll
            for (int ni = 0; ni < 4; ++ni)
                acc[mi][ni] = __builtin_amdgcn_mfma_f32_16x16x32_bf16(af[mi], bfr[ni], acc[mi][ni], 0, 0, 0);
        __syncthreads();
    }
    #pragma unroll
    for (int mi = 0; mi < 4; ++mi) {
        #pragma unroll
        for (int ni = 0; ni < 4; ++ni) {
            int col = bn0 + wn + ni * 16 + lm;
            #pragma unroll
            for (int r = 0; r < 4; ++r) {
                int row = bm0 + wm + mi * 16 + quad * 4 + r;
                if (row < N_NODES)
                    Cb[(size_t)row * 256 + col] = f2bf(acc[mi][ni][r]);
            }
        }
    }
    // fused elr1: wave's 64 cols = 2 heads
    float alv[4], arv[4];
    #pragma unroll
    for (int ni = 0; ni < 4; ++ni) {
        int colg = bn0 + wn + ni * 16 + lm;
        alv[ni] = al1[colg];
        arv[ni] = ar1[colg];
    }
    int head0 = (bn0 + wn) >> 5;
    #pragma unroll
    for (int g = 0; g < 2; ++g) {
        #pragma unroll
        for (int mi = 0; mi < 4; ++mi) {
            #pragma unroll
            for (int r = 0; r < 4; ++r) {
                float pel = acc[mi][2 * g][r] * alv[2 * g] + acc[mi][2 * g + 1][r] * alv[2 * g + 1];
                float per = acc[mi][2 * g][r] * arv[2 * g] + acc[mi][2 * g + 1][r] * arv[2 * g + 1];
                #pragma unroll
                for (int m = 1; m <= 8; m <<= 1) {
                    pel += __shfl_xor(pel, m, 64);
                    per += __shfl_xor(per, m, 64);
                }
                if (lm == 0) {
                    int row = bm0 + wm + mi * 16 + quad * 4 + r;
                    if (row < N_NODES) {
                        el1[row * 8 + head0 + g] = pel;
                        er1[row * 8 + head0 + g] = per;
                    }
                }
            }
        }
    }
}

// ---------------- L1 aggregation: one wave per dst node (8-edge batched unroll) ----------------

__global__ __launch_bounds__(256) void k_agg1(const unsigned short* __restrict__ feat1b,
                                              const float* __restrict__ el1, const float* __restrict__ er1,
                                              const float* __restrict__ x, const float* __restrict__ b1,
                                              const int* __restrict__ rowoff, const int* __restrict__ csr_src,
                                              unsigned short* __restrict__ y_b) {
    int v = (blockIdx.x * 256 + threadIdx.x) >> 6;
    int lane = threadIdx.x & 63;
    if (v >= N_NODES) return;
    int h = lane >> 3;
    float er = er1[v * 8 + h];
    int c0 = lane * 4;
    float ax = 0.f, ay = 0.f, az = 0.f, aw = 0.f, wsum = 0.f;
    int s = rowoff[v], e = rowoff[v + 1];
    int j = s;
    for (; j + 7 < e; j += 8) {
        int u[8];
        #pragma unroll
        for (int q = 0; q < 8; ++q) u[q] = csr_src[j + q];
        float tt[8];
        #pragma unroll
        for (int q = 0; q < 8; ++q) tt[q] = el1[u[q] * 8 + h] + er;
        ushort4 hv[8];
        #pragma unroll
        for (int q = 0; q < 8; ++q) hv[q] = *(const ushort4*)(feat1b + (size_t)u[q] * 256 + c0);
        #pragma unroll
        for (int q = 0; q < 8; ++q) {
            float tq = tt[q] > 0.f ? tt[q] : NEG_SLOPE * tt[q];
            float w = __expf(tq);
            wsum += w;
            ax += w * bf2f(hv[q].x);
            ay += w * bf2f(hv[q].y);
            az += w * bf2f(hv[q].z);
            aw += w * bf2f(hv[q].w);
        }
    }
    for (; j + 3 < e; j += 4) {
        int u[4];
        #pragma unroll
        for (int q = 0; q < 4; ++q) u[q] = csr_src[j + q];
        float tt[4];
        #pragma unroll
        for (int q = 0; q < 4; ++q) tt[q] = el1[u[q] * 8 + h] + er;
        ushort4 hv[4];
        #pragma unroll
        for (int q = 0; q < 4; ++q) hv[q] = *(const ushort4*)(feat1b + (size_t)u[q] * 256 + c0);
        #pragma unroll
        for (int q = 0; q < 4; ++q) {
            float tq = tt[q] > 0.f ? tt[q] : NEG_SLOPE * tt[q];
            float w = __expf(tq);
            wsum += w;
            ax += w * bf2f(hv[q].x);
            ay += w * bf2f(hv[q].y);
            az += w * bf2f(hv[q].z);
            aw += w * bf2f(hv[q].w);
        }
    }
    for (; j < e; ++j) {
        int u = csr_src[j];
        float t = el1[u * 8 + h] + er;
        ushort4 hh = *(const ushort4*)(feat1b + (size_t)u * 256 + c0);
        t = t > 0.f ? t : NEG_SLOPE * t;
        float w = __expf(t);
        wsum += w;
        ax += w * bf2f(hh.x);
        ay += w * bf2f(hh.y);
        az += w * bf2f(hh.z);
        aw += w * bf2f(hh.w);
    }
    float inv = (e > s) ? 1.f / wsum : 0.f;
    float4 r = *(const float4*)(x + (size_t)v * 256 + c0);
    float4 bb = *(const float4*)(b1 + c0);
    ushort4 o;
    o.x = f2bf(fmaxf(ax * inv + r.x + bb.x, 0.f));
    o.y = f2bf(fmaxf(ay * inv + r.y + bb.y, 0.f));
    o.z = f2bf(fmaxf(az * inv + r.z + bb.z, 0.f));
    o.w = f2bf(fmaxf(aw * inv + r.w + bb.w, 0.f));
    *(ushort4*)(y_b + (size_t)v * 256 + c0) = o;
}

// ---------------- GEMM2 + fused elr2: [feat2b|res2] = y_b @ [W2|resW2] ----------------

__global__ __launch_bounds__(256) void k_gemm2f(const unsigned short* __restrict__ Ab,
                                                const unsigned short* __restrict__ BT,  // [64][256]
                                                const float* __restrict__ al2, const float* __restrict__ ar2,
                                                unsigned short* __restrict__ feat2b, float* __restrict__ res2,
                                                float* __restrict__ el2, float* __restrict__ er2) {
    __shared__ unsigned short As[128 * 32];
    __shared__ unsigned short Bs[64 * 32];
    const int t = threadIdx.x;
    const int bm0 = blockIdx.x * 128;
    const int wave = t >> 6, lane = t & 63;
    const int wm = (wave & 1) * 64, wn = (wave >> 1) * 32;
    const int lm = lane & 15, quad = lane >> 4;
    const int lrow = lane >> 2;
    const int lchk = (lane & 3) * 8;

    f32x4 acc[4][2];
    #pragma unroll
    for (int i = 0; i < 4; ++i)
        #pragma unroll
        for (int j = 0; j < 2; ++j)
            #pragma unroll
            for (int r = 0; r < 4; ++r) acc[i][j][r] = 0.f;

    for (int k0 = 0; k0 < 256; k0 += 32) {
        #pragma unroll
        for (int i = 0; i < 2; ++i) {
            int r0 = wave * 32 + i * 16;
            gload_lds16(Ab + (size_t)(bm0 + r0 + lrow) * 256 + k0 + lchk, &As[r0 * 32]);
        }
        {
            int r0 = wave * 16;
            gload_lds16(BT + (size_t)(r0 + lrow) * 256 + k0 + lchk, &Bs[r0 * 32]);
        }
        __syncthreads();
        bf16x8 af[4], bfr[2];
        #pragma unroll
        for (int i = 0; i < 4; ++i)
            af[i] = *(const bf16x8*)(&As[(wm + i * 16 + lm) * 32 + quad * 8]);
        #pragma unroll
        for (int i = 0; i < 2; ++i)
            bfr[i] = *(const bf16x8*)(&Bs[(wn + i * 16 + lm) * 32 + quad * 8]);
        #pragma unroll
        for (int mi = 0; mi < 4; ++mi)
            #pragma unroll
            for (int ni = 0; ni < 2; ++ni)
                acc[mi][ni] = __builtin_amdgcn_mfma_f32_16x16x32_bf16(af[mi], bfr[ni], acc[mi][ni], 0, 0, 0);
        __syncthreads();
    }
    #pragma unroll
    for (int mi = 0; mi < 4; ++mi) {
        #pragma unroll
        for (int ni = 0; ni < 2; ++ni) {
            int col = wn + ni * 16 + lm;  // 0..63
            #pragma unroll
            for (int r = 0; r < 4; ++r) {
                int row = bm0 + wm + mi * 16 + quad * 4 + r;
                if (row < N_NODES) {
                    float val = acc[mi][ni][r];
                    if (col < 32) feat2b[(size_t)row * 32 + col] = f2bf(val);
                    else          res2[(size_t)row * 32 + col - 32] = val;
                }
            }
        }
    }
    if (wn == 0) {
        float alv[2], arv[2];
        #pragma unroll
        for (int ni = 0; ni < 2; ++ni) {
            alv[ni] = al2[ni * 16 + lm];
            arv[ni] = ar2[ni * 16 + lm];
        }
        #pragma unroll
        for (int mi = 0; mi < 4; ++mi) {
            #pragma unroll
            for (int r = 0; r < 4; ++r) {
                float pel = acc[mi][0][r] * alv[0] + acc[mi][1][r] * alv[1];
                float per = acc[mi][0][r] * arv[0] + acc[mi][1][r] * arv[1];
                #pragma unroll
                for (int m = 1; m <= 8; m <<= 1) {
                    pel += __shfl_xor(pel, m, 64);
                    per += __shfl_xor(per, m, 64);
                }
                if (lm == 0) {
                    int row = bm0 + wm + mi * 16 + quad * 4 + r;
                    if (row < N_NODES) {
                        el2[row] = pel;
                        er2[row] = per;
                    }
                }
            }
        }
    }
}

// ---------------- L2 aggregation: 32 lanes per dst node (4-edge batched unroll) ----------------

__global__ __launch_bounds__(256) void k_agg2(const unsigned short* __restrict__ feat2b,
                                              const float* __restrict__ el2, const float* __restrict__ er2,
                                              const float* __restrict__ res2, const float* __restrict__ b2,
                                              const int* __restrict__ rowoff, const int* __restrict__ csr_src,
                                              float* __restrict__ out) {
    int g = blockIdx.x * 256 + threadIdx.x;
    int v = g >> 5;
    int c = g & 31;
    if (v >= N_NODES) return;
    float er = er2[v];
    float acc = 0.f, wsum = 0.f;
    int s = rowoff[v], e = rowoff[v + 1];
    int j = s;
    for (; j + 3 < e; j += 4) {
        int u[4];
        #pragma unroll
        for (int q = 0; q < 4; ++q) u[q] = csr_src[j + q];
        float tt[4];
        #pragma unroll
        for (int q = 0; q < 4; ++q) tt[q] = el2[u[q]] + er;
        unsigned short fv[4];
        #pragma unroll
        for (int q = 0; q < 4; ++q) fv[q] = feat2b[(size_t)u[q] * 32 + c];
        #pragma unroll
        for (int q = 0; q < 4; ++q) {
            float tq = tt[q] > 0.f ? tt[q] : NEG_SLOPE * tt[q];
            float w = __expf(tq);
            wsum += w;
            acc += w * bf2f(fv[q]);
        }
    }
    for (; j < e; ++j) {
        int u = csr_src[j];
        float t = el2[u] + er;
        t = t > 0.f ? t : NEG_SLOPE * t;
        float w = __expf(t);
        wsum += w;
        acc += w * bf2f(feat2b[(size_t)u * 32 + c]);
    }
    float inv = (e > s) ? 1.f / wsum : 0.f;
    out[(size_t)v * 32 + c] = acc * inv + res2[(size_t)v * 32 + c] + b2[c];
}

// ---------------- launch ----------------

extern "C" void kernel_launch(void* const* d_in, const int* in_sizes, int n_in,
                              void* d_out, int out_size, void* d_ws, size_t ws_size,
                              hipStream_t stream) {
    const float* x     = (const float*)d_in[0];
    const int*   src   = (const int*)d_in[1];
    const int*   dst   = (const int*)d_in[2];
    const float* W1    = (const float*)d_in[3];
    const float* al1   = (const float*)d_in[4];
    const float* ar1   = (const float*)d_in[5];
    const float* b1    = (const float*)d_in[6];
    const float* W2    = (const float*)d_in[7];
    const float* al2   = (const float*)d_in[8];
    const float* ar2   = (const float*)d_in[9];
    const float* resW2 = (const float*)d_in[10];
    const float* b2    = (const float*)d_in[11];
    float* out = (float*)d_out;

    char* ws = (char*)d_ws;
    size_t off = 0;
    auto alloc = [&](size_t bytes) {
        void* p = ws + off;
        off += (bytes + 255) & ~(size_t)255;
        return p;
    };
    unsigned short* feat1b = (unsigned short*)alloc((size_t)N_NODES * 256 * 2);
    unsigned short* y_b    = (unsigned short*)alloc((size_t)M_PAD * 256 * 2);
    unsigned short* W1T    = (unsigned short*)alloc((size_t)256 * 256 * 2);
    unsigned short* W2T    = (unsigned short*)alloc((size_t)64 * 256 * 2);
    unsigned short* feat2b = (unsigned short*)alloc((size_t)N_NODES * 32 * 2);
    float* res2   = (float*)alloc((size_t)N_NODES * 32 * 4);
    float* el1    = (float*)alloc((size_t)N_NODES * 8 * 4);
    float* er1    = (float*)alloc((size_t)N_NODES * 8 * 4);
    float* el2    = (float*)alloc((size_t)N_NODES * 4);
    float* er2    = (float*)alloc((size_t)N_NODES * 4);
    int*   deg    = (int*)alloc((size_t)N_NODES * 4);
    int*   rowoff = (int*)alloc((size_t)(N_NODES + 1) * 4);
    int*   wp     = (int*)alloc((size_t)N_NODES * 4);
    int*   bsum   = (int*)alloc((size_t)SCAN_NB * 4);
    int*   csr    = (int*)alloc((size_t)N_EDGES * 4);
    (void)ws_size;

    // weights transpose + deg zeroing (replaces memset dispatch)
    k_trans<<<dim3(10, 8), 256, 0, stream>>>(W1, W2, resW2, W1T, W2T, deg);

    // CSR build (rebuilt every call) — multi-block; scan2 folded into scan3
    k_hist<<<(N_EDGES + 255) / 256, 256, 0, stream>>>(dst, deg);
    k_scan1<<<SCAN_NB, SCAN_BLK, 0, stream>>>(deg, rowoff, bsum);
    k_scan3<<<SCAN_NB, SCAN_BLK, 0, stream>>>(deg, rowoff, wp, bsum);
    k_scatter<<<(N_EDGES + 255) / 256, 256, 0, stream>>>(src, dst, wp, csr);

    // Layer 1
    k_gemm1f<<<dim3(M_PAD / 128, 2), 256, 0, stream>>>(x, W1T, al1, ar1, feat1b, el1, er1);
    k_agg1<<<(N_NODES * 64) / 256, 256, 0, stream>>>(feat1b, el1, er1, x, b1, rowoff, csr, y_b);

    // Layer 2
    k_gemm2f<<<M_PAD / 128, 256, 0, stream>>>(y_b, W2T, al2, ar2, feat2b, res2, el2, er2);
    k_agg2<<<(N_NODES * 32) / 256, 256, 0, stream>>>(feat2b, el2, er2, res2, b2, rowoff, csr, out);
}